// Round 8
// baseline (1541.478 us; speedup 1.0000x reference)
//
#include <hip/hip_runtime.h>
#include <hip/hip_bf16.h>

// WindowAttention (Swin) on MI355X — round 8: FULL FUSION
//   k_cvt_w : weights fp32 -> bf16 B^T (n-major)
//   k_cvt   : x fp32 -> bf16
//   k_fused : per window-block: qkv GEMM (frags from global xb + L2 weights)
//             -> attention (verbatim R2 softmax/PV) -> O in LDS -> proj GEMM
//             -> fp32 out.  No qkv/O intermediates in HBM, no standalone GEMMs.
// Rationale: R3/R4/R5/R7 proved the short-K streaming GEMMs are latency-bound
// at ~415us each regardless of schedule (equal block-K-steps -> equal time).

typedef __attribute__((ext_vector_type(8))) short bf16x8;
typedef __attribute__((ext_vector_type(4))) float f32x4;

#define SEQ_N  49
#define CH     384
#define QKV_N  1152
#define M_TOT  200704   // 4096 windows * 49

__device__ __forceinline__ unsigned short f2b(float f) {
    union { float f; unsigned int u; } v; v.f = f;
    return (unsigned short)((v.u + 0x7FFFu + ((v.u >> 16) & 1u)) >> 16);
}

__device__ __forceinline__ bf16x8 ld8(const unsigned short* p) {
    return *(const bf16x8*)p;    // 16B-aligned at every call site
}

// ---------------- weight convert+transpose: Bt[n][k] = bf16(W[k][n]) --------
__global__ __launch_bounds__(256) void k_cvt_w(const float* __restrict__ wq,
        const float* __restrict__ wp, unsigned short* __restrict__ oq,
        unsigned short* __restrict__ op)
{
    int t = blockIdx.x * 256 + threadIdx.x;
    if (t < QKV_N * CH) {
        int n = t / CH, k = t - n * CH;
        oq[t] = f2b(wq[(size_t)k * QKV_N + n]);
    }
    if (t < CH * CH) {
        int n = t / CH, k = t - n * CH;
        op[t] = f2b(wp[(size_t)k * CH + n]);
    }
}

// ---------------- x fp32 -> bf16 (vectorized, grid-stride) -------------------
__global__ __launch_bounds__(256) void k_cvt(const float* __restrict__ in,
        unsigned short* __restrict__ outp, int n8)
{
    int stride = gridDim.x * 256;
    for (int i = blockIdx.x * 256 + threadIdx.x; i < n8; i += stride) {
        const float4* p = (const float4*)(in + (size_t)i * 8);
        float4 a = p[0], b = p[1];
        uint4 v;
        v.x = (unsigned)f2b(a.x) | ((unsigned)f2b(a.y) << 16);
        v.y = (unsigned)f2b(a.z) | ((unsigned)f2b(a.w) << 16);
        v.z = (unsigned)f2b(b.x) | ((unsigned)f2b(b.y) << 16);
        v.w = (unsigned)f2b(b.z) | ((unsigned)f2b(b.w) << 16);
        *(uint4*)(outp + (size_t)i * 8) = v;
    }
}

// ---------------- fused window attention ------------------------------------
// 1 block = 1 window (49 rows), 4 waves. Wave wv handles heads {wv, wv+4, wv+8}.
// LDS: O_lds [64][392] shared + per-wave q[64][40], k[64][40], Vt[32][72],
//      Pw[64][72].  Total 146,432 B.
__global__ __launch_bounds__(256, 1) void k_fused(
        const unsigned short* __restrict__ xb,     // [M_TOT][384] bf16
        const unsigned short* __restrict__ wq_bt,  // [1152][384] bf16 n-major
        const unsigned short* __restrict__ wp_bt,  // [384][384]  bf16 n-major
        const float* __restrict__ qkv_b,
        const float* __restrict__ proj_b,
        const float* __restrict__ mask,
        const float* __restrict__ btab,
        float* __restrict__ out)
{
    extern __shared__ unsigned short sm[];
    const int tid = threadIdx.x;
    const int lane = tid & 63, wv = tid >> 6;
    const int l15 = lane & 15, g = lane >> 4;
    const int win = blockIdx.x;
    const int wimg = win & 63;

    unsigned short* O_lds = sm;                               // 64*392
    unsigned short* qw = sm + 25088 + wv * 12032;             // 64*40
    unsigned short* kw = qw + 2560;                           // 64*40
    unsigned short* Vt = kw + 2560;                           // 32*72
    unsigned short* Pw = Vt + 2304;                           // 64*72

    const unsigned short* xrow = xb + (size_t)win * SEQ_N * CH;

    int rc[4];
#pragma unroll
    for (int mt = 0; mt < 4; ++mt) {
        int r = mt * 16 + l15; rc[mt] = r > 48 ? 48 : r;
    }

    int jj[4], jh[4], jw4[4];
#pragma unroll
    for (int nt = 0; nt < 4; ++nt) {
        int j = nt * 16 + l15;
        jj[nt] = j; jh[nt] = j / 7; jw4[nt] = j - (j / 7) * 7;
    }
    const float scale = 0.17677669529663687f;   // 32^-0.5

    for (int hi = 0; hi < 3; ++hi) {
        const int h = wv + hi * 4;
        const int co = h * 32;

        // ---- qkv GEMM for this head: acc[mat][mt][nt], A-frags shared q/k/v
        f32x4 acc[3][4][2];
#pragma unroll
        for (int m = 0; m < 3; ++m)
#pragma unroll
            for (int a = 0; a < 4; ++a)
#pragma unroll
                for (int b = 0; b < 2; ++b) acc[m][a][b] = (f32x4){0.f,0.f,0.f,0.f};

        for (int ks = 0; ks < 12; ++ks) {
            bf16x8 af[4];
#pragma unroll
            for (int mt = 0; mt < 4; ++mt)
                af[mt] = ld8(xrow + (size_t)rc[mt] * CH + ks * 32 + g * 8);
#pragma unroll
            for (int m = 0; m < 3; ++m)
#pragma unroll
                for (int nt = 0; nt < 2; ++nt) {
                    bf16x8 bf = ld8(wq_bt +
                        (size_t)(m * 384 + co + nt * 16 + l15) * CH + ks * 32 + g * 8);
#pragma unroll
                    for (int mt = 0; mt < 4; ++mt)
                        acc[m][mt][nt] = __builtin_amdgcn_mfma_f32_16x16x32_bf16(
                                af[mt], bf, acc[m][mt][nt], 0, 0, 0);
                }
        }

        // ---- q,k -> row-major LDS (+bias); v -> Vt transposed (+bias, pad=0)
#pragma unroll
        for (int nt = 0; nt < 2; ++nt) {
            int c = nt * 16 + l15;
            float bq = qkv_b[co + c];
            float bk = qkv_b[384 + co + c];
            float bv = qkv_b[768 + co + c];
#pragma unroll
            for (int mt = 0; mt < 4; ++mt) {
#pragma unroll
                for (int r = 0; r < 4; ++r) {
                    int row = mt * 16 + g * 4 + r;
                    qw[row * 40 + c] = f2b(acc[0][mt][nt][r] + bq);
                    kw[row * 40 + c] = f2b(acc[1][mt][nt][r] + bk);
                }
                ushort4 pv4;
#pragma unroll
                for (int r = 0; r < 4; ++r) {
                    int krow = mt * 16 + g * 4 + r;
                    unsigned short vv = f2b(acc[2][mt][nt][r] + bv);
                    ((unsigned short*)&pv4)[r] = (krow < SEQ_N) ? vv : (unsigned short)0;
                }
                *(ushort4*)&Vt[c * 72 + mt * 16 + g * 4] = pv4;
            }
        }

        // ---- S = q @ k^T (same-wave LDS produce->consume)
        bf16x8 qf[4], kf[4];
#pragma unroll
        for (int mt = 0; mt < 4; ++mt) qf[mt] = ld8(&qw[(mt * 16 + l15) * 40 + g * 8]);
#pragma unroll
        for (int nt = 0; nt < 4; ++nt) kf[nt] = ld8(&kw[(nt * 16 + l15) * 40 + g * 8]);
        f32x4 sa[4][4];
#pragma unroll
        for (int mt = 0; mt < 4; ++mt)
#pragma unroll
            for (int nt = 0; nt < 4; ++nt) sa[mt][nt] = (f32x4){0.f,0.f,0.f,0.f};
#pragma unroll
        for (int mt = 0; mt < 4; ++mt)
#pragma unroll
            for (int nt = 0; nt < 4; ++nt)
                sa[mt][nt] = __builtin_amdgcn_mfma_f32_16x16x32_bf16(
                        qf[mt], kf[nt], sa[mt][nt], 0, 0, 0);

        // ---- scale + bias + mask + row softmax -> Pw (verbatim R2)
#pragma unroll
        for (int mt = 0; mt < 4; ++mt) {
#pragma unroll
            for (int r = 0; r < 4; ++r) {
                int i = mt * 16 + g * 4 + r;
                int ic = i < 49 ? i : 48;
                int ih = ic / 7, iw = ic - (ic / 7) * 7;
                const float* mrow = mask + (size_t)wimg * 2401 + ic * 49;
                float sv[4];
#pragma unroll
                for (int nt = 0; nt < 4; ++nt) {
                    float s = sa[mt][nt][r];
                    if (jj[nt] < 49) {
                        int idx = (ih - jh[nt] + 6) * 13 + (iw - jw4[nt] + 6);
                        s = s * scale + btab[idx * 12 + h] + mrow[jj[nt]];
                    } else s = -1e30f;
                    sv[nt] = s;
                }
                float mx = fmaxf(fmaxf(sv[0], sv[1]), fmaxf(sv[2], sv[3]));
#pragma unroll
                for (int d = 1; d < 16; d <<= 1) mx = fmaxf(mx, __shfl_xor(mx, d));
                float sum = 0.f;
#pragma unroll
                for (int nt = 0; nt < 4; ++nt) { sv[nt] = __expf(sv[nt] - mx); sum += sv[nt]; }
#pragma unroll
                for (int d = 1; d < 16; d <<= 1) sum += __shfl_xor(sum, d);
                float inv = 1.0f / sum;
#pragma unroll
                for (int nt = 0; nt < 4; ++nt)
                    Pw[i * 72 + nt * 16 + l15] = f2b(sv[nt] * inv);
            }
        }

        // ---- O = P @ V (verbatim R2)
        f32x4 oa[4][2];
#pragma unroll
        for (int mt = 0; mt < 4; ++mt)
#pragma unroll
            for (int nt = 0; nt < 2; ++nt) oa[mt][nt] = (f32x4){0.f,0.f,0.f,0.f};
#pragma unroll
        for (int ks2 = 0; ks2 < 2; ++ks2) {
            bf16x8 pf[4];
#pragma unroll
            for (int mt = 0; mt < 4; ++mt)
                pf[mt] = ld8(Pw + (mt * 16 + l15) * 72 + ks2 * 32 + g * 8);
#pragma unroll
            for (int nt = 0; nt < 2; ++nt) {
                bf16x8 vf = ld8(Vt + (nt * 16 + l15) * 72 + ks2 * 32 + g * 8);
#pragma unroll
                for (int mt = 0; mt < 4; ++mt)
                    oa[mt][nt] = __builtin_amdgcn_mfma_f32_16x16x32_bf16(
                            pf[mt], vf, oa[mt][nt], 0, 0, 0);
            }
        }

        // ---- O_h -> O_lds cols [co .. co+31]
#pragma unroll
        for (int mt = 0; mt < 4; ++mt)
#pragma unroll
            for (int r = 0; r < 4; ++r) {
                int row = mt * 16 + g * 4 + r;
#pragma unroll
                for (int nt = 0; nt < 2; ++nt)
                    O_lds[row * 392 + co + nt * 16 + l15] = f2b(oa[mt][nt][r]);
            }
        __syncthreads();   // uniform; orders LDS phases across head iterations
    }

    // ---- proj: out[win rows][384] = O_lds @ wp_bt^T + proj_b  (K=384 on-chip)
    f32x4 pacc[4][6];
#pragma unroll
    for (int a = 0; a < 4; ++a)
#pragma unroll
        for (int b = 0; b < 6; ++b) pacc[a][b] = (f32x4){0.f,0.f,0.f,0.f};

    for (int ks = 0; ks < 12; ++ks) {
        bf16x8 paf[4];
#pragma unroll
        for (int mt = 0; mt < 4; ++mt)
            paf[mt] = ld8(&O_lds[(mt * 16 + l15) * 392 + ks * 32 + g * 8]);
#pragma unroll
        for (int nt = 0; nt < 6; ++nt) {
            bf16x8 pbf = ld8(wp_bt +
                (size_t)(wv * 96 + nt * 16 + l15) * CH + ks * 32 + g * 8);
#pragma unroll
            for (int mt = 0; mt < 4; ++mt)
                pacc[mt][nt] = __builtin_amdgcn_mfma_f32_16x16x32_bf16(
                        paf[mt], pbf, pacc[mt][nt], 0, 0, 0);
        }
    }

#pragma unroll
    for (int mt = 0; mt < 4; ++mt)
#pragma unroll
        for (int nt = 0; nt < 6; ++nt) {
            int col = wv * 96 + nt * 16 + l15;
            float bb = proj_b[col];
#pragma unroll
            for (int r = 0; r < 4; ++r) {
                int row = mt * 16 + g * 4 + r;
                if (row < SEQ_N)
                    out[(size_t)(win * SEQ_N + row) * CH + col] = pacc[mt][nt][r] + bb;
            }
        }
}

extern "C" void kernel_launch(void* const* d_in, const int* in_sizes, int n_in,
                              void* d_out, int out_size, void* d_ws, size_t ws_size,
                              hipStream_t stream) {
    const float* x      = (const float*)d_in[0];
    const float* mask   = (const float*)d_in[1];
    const float* qkv_w  = (const float*)d_in[2];
    const float* qkv_b  = (const float*)d_in[3];
    const float* proj_w = (const float*)d_in[4];
    const float* proj_b = (const float*)d_in[5];
    const float* btab   = (const float*)d_in[6];
    float* out = (float*)d_out;

    unsigned short* wq_bt = (unsigned short*)d_ws;              // 442368
    unsigned short* wp_bt = wq_bt + QKV_N * CH;                 // 147456
    unsigned short* xb    = wp_bt + CH * CH;                    // 77070336
    const size_t need = ((size_t)QKV_N * CH + (size_t)CH * CH
                         + (size_t)M_TOT * CH) * 2;             // ~155.3 MB
    if (ws_size < need) return;

    const int smem = 146432;   // bytes (see k_fused layout)
    hipFuncSetAttribute(reinterpret_cast<const void*>(k_fused),
                        hipFuncAttributeMaxDynamicSharedMemorySize, smem);

    dim3 blk(256);
    k_cvt_w<<<dim3((QKV_N * CH + 255) / 256), blk, 0, stream>>>(qkv_w, proj_w, wq_bt, wp_bt);
    k_cvt  <<<dim3(2048), blk, 0, stream>>>(x, xb, M_TOT * CH / 8);
    k_fused<<<dim3(4096), blk, smem, stream>>>(xb, wq_bt, wp_bt, qkv_b, proj_b,
                                               mask, btab, out);
}

// Round 9
// 1136.049 us; speedup vs baseline: 1.3569x; 1.3569x over previous
//
#include <hip/hip_runtime.h>
#include <hip/hip_bf16.h>

// WindowAttention (Swin) on MI355X — round 9
//   Change vs R7: k_gemm tile geometry 128x128 -> 192x384 (8 waves, 96x96 per
//   wave). Evidence R3-R7: time ~ staged-LDS bytes (169K block-K-steps x 16KB
//   = 2.71 GB at ~6.5 TB/s chip staging rate = 415us, schedule-invariant).
//   192x384 cuts staged bytes to 1.39 GB (qkv) / 0.46 GB (proj) and
//   block-K-steps to 37.7K each. Counted-vmcnt dbuf kept (per-wave 5/4).
//   k_attn / k_cvt / k_cvt_w unchanged (R8 fusion regressed; reverted).

typedef __attribute__((ext_vector_type(8))) short bf16x8;
typedef __attribute__((ext_vector_type(4))) float f32x4;

#define SEQ_N  49
#define CH     384
#define QKV_N  1152
#define UNIT_ROWS 3136   // 64 windows * 49 rows

__device__ __forceinline__ unsigned short f2b(float f) {
    union { float f; unsigned int u; } v; v.f = f;
    return (unsigned short)((v.u + 0x7FFFu + ((v.u >> 16) & 1u)) >> 16);
}

__device__ __forceinline__ bf16x8 ld8(const unsigned short* p) {
    return *(const bf16x8*)p;    // 16B-aligned at every call site
}

// async global->LDS, 16B per lane; lds dst must be wave-uniform base
__device__ __forceinline__ void gload16(const unsigned short* g, unsigned short* l) {
    __builtin_amdgcn_global_load_lds(
        (const __attribute__((address_space(1))) unsigned int*)g,
        (__attribute__((address_space(3))) unsigned int*)l, 16, 0, 0);
}

// bijective XCD-chunking swizzle (m204)
__device__ __forceinline__ int xcd_swizzle(int orig, int T) {
    int q = T >> 3, r = T & 7;
    int xcd = orig & 7, idx = orig >> 3;
    return (xcd < r ? xcd * (q + 1) : r * (q + 1) + (xcd - r) * q) + idx;
}

// ---------------- weight convert+transpose: Bt[n][k] = bf16(W[k][n]) --------
__global__ __launch_bounds__(256) void k_cvt_w(const float* __restrict__ wq,
        const float* __restrict__ wp, unsigned short* __restrict__ oq,
        unsigned short* __restrict__ op)
{
    int t = blockIdx.x * 256 + threadIdx.x;
    if (t < QKV_N * CH) {
        int n = t / CH, k = t - n * CH;
        oq[t] = f2b(wq[(size_t)k * QKV_N + n]);
    }
    if (t < CH * CH) {
        int n = t / CH, k = t - n * CH;
        op[t] = f2b(wp[(size_t)k * CH + n]);
    }
}

// ---------------- x fp32 -> bf16 (vectorized, grid-stride) -------------------
__global__ __launch_bounds__(256) void k_cvt(const float* __restrict__ in,
        unsigned short* __restrict__ outp, int n8)
{
    int stride = gridDim.x * 256;
    for (int i = blockIdx.x * 256 + threadIdx.x; i < n8; i += stride) {
        const float4* p = (const float4*)(in + (size_t)i * 8);
        float4 a = p[0], b = p[1];
        uint4 v;
        v.x = (unsigned)f2b(a.x) | ((unsigned)f2b(a.y) << 16);
        v.y = (unsigned)f2b(a.z) | ((unsigned)f2b(a.w) << 16);
        v.z = (unsigned)f2b(b.x) | ((unsigned)f2b(b.y) << 16);
        v.w = (unsigned)f2b(b.z) | ((unsigned)f2b(b.w) << 16);
        *(uint4*)(outp + (size_t)i * 8) = v;
    }
}

// ---------------- big-tile GEMM: C[M][ldc] = A @ Bt^T + bias -----------------
// A bf16 row-major [M][lda], Bt bf16 n-major [N][K]. Tile 192x384, BK=32,
// 8 waves, 96x96 per wave, dbuf LDS + counted vmcnt (per-wave 5/4 loads).
template<int OUTF32>
__global__ __launch_bounds__(512, 2) void k_gemm(
        const unsigned short* __restrict__ A, int lda,
        const unsigned short* __restrict__ Bt, int K,
        const float* __restrict__ bias,
        unsigned short* __restrict__ Cb, float* __restrict__ Cf, int ldc,
        int M, int ntiles, int mtiles)
{
    __shared__ unsigned short As[2 * 6144];    // [buf][192][32]
    __shared__ unsigned short Bs[2 * 12288];   // [buf][384][32]
    const int wg = xcd_swizzle(blockIdx.x, mtiles * ntiles);
    const int m0 = (wg / ntiles) * 192;
    const int n0 = (wg % ntiles) * 384;
    const int tid = threadIdx.x;
    const int lane = tid & 63, wv = tid >> 6;
    const int wr = wv >> 2, wc = wv & 3;       // wave tile (96x96) origin
    const int l15 = lane & 15, g = lane >> 4;

    f32x4 acc[6][6];
#pragma unroll
    for (int a = 0; a < 6; ++a)
#pragma unroll
        for (int b = 0; b < 6; ++b) acc[a][b] = (f32x4){0.f, 0.f, 0.f, 0.f};

    // staging sources: lane covers row base+(lane>>2), k elems (lane&3)*8..+7
    const int lrow = lane >> 2, kofs = (lane & 3) * 8;
    const int raStart = (wv < 4) ? (wv * 32) : (128 + (wv - 4) * 16);
    int ra0 = m0 + raStart + lrow;      if (ra0 > M - 1) ra0 = M - 1;
    int ra1 = m0 + raStart + 16 + lrow; if (ra1 > M - 1) ra1 = M - 1; // wv<4 only
    const unsigned short* a0p = A + (size_t)ra0 * lda + kofs;
    const unsigned short* a1p = A + (size_t)ra1 * lda + kofs;
    const unsigned short* b0p = Bt + (size_t)(n0 +       wv * 16 + lrow) * K + kofs;
    const unsigned short* b1p = Bt + (size_t)(n0 + 128 + wv * 16 + lrow) * K + kofs;
    const unsigned short* b2p = Bt + (size_t)(n0 + 256 + wv * 16 + lrow) * K + kofs;
    const int laA0 = raStart * 32;             // elem offsets (+buf*6144)
    const int laA1 = (raStart + 16) * 32;
    const int lb0 = (      wv * 16) * 32;      // (+buf*12288)
    const int lb1 = (128 + wv * 16) * 32;
    const int lb2 = (256 + wv * 16) * 32;

#define STAGE(kt, buf) do {                                     \
        if (wv < 4) {                                           \
            gload16(a0p + (kt), &As[(buf) * 6144 + laA0]);      \
            gload16(a1p + (kt), &As[(buf) * 6144 + laA1]);      \
        } else {                                                \
            gload16(a0p + (kt), &As[(buf) * 6144 + laA0]);      \
        }                                                       \
        gload16(b0p + (kt), &Bs[(buf) * 12288 + lb0]);          \
        gload16(b1p + (kt), &Bs[(buf) * 12288 + lb1]);          \
        gload16(b2p + (kt), &Bs[(buf) * 12288 + lb2]);          \
    } while (0)

    const int ns = K >> 5;                     // 12 (qkv) or 36 (proj)
    STAGE(0, 0);
    int buf = 0;
    for (int t = 0; t < ns; ++t) {
        if (t + 1 < ns) {
            STAGE((t + 1) * 32, buf ^ 1);
            __builtin_amdgcn_sched_barrier(0);
            if (wv < 4) asm volatile("s_waitcnt vmcnt(5)" ::: "memory");
            else        asm volatile("s_waitcnt vmcnt(4)" ::: "memory");
        } else {
            __builtin_amdgcn_sched_barrier(0);
            asm volatile("s_waitcnt vmcnt(0)" ::: "memory");
        }
        __builtin_amdgcn_sched_barrier(0);
        __builtin_amdgcn_s_barrier();          // tile-t staged for all waves
        __builtin_amdgcn_sched_barrier(0);
        bf16x8 af[6], bfr[6];
#pragma unroll
        for (int mt = 0; mt < 6; ++mt)
            af[mt] = ld8(&As[buf * 6144 + (wr * 96 + mt * 16 + l15) * 32 + g * 8]);
#pragma unroll
        for (int nt = 0; nt < 6; ++nt)
            bfr[nt] = ld8(&Bs[buf * 12288 + (wc * 96 + nt * 16 + l15) * 32 + g * 8]);
#pragma unroll
        for (int mt = 0; mt < 6; ++mt)
#pragma unroll
            for (int nt = 0; nt < 6; ++nt)
                acc[mt][nt] = __builtin_amdgcn_mfma_f32_16x16x32_bf16(
                        af[mt], bfr[nt], acc[mt][nt], 0, 0, 0);
        __builtin_amdgcn_sched_barrier(0);
        __builtin_amdgcn_s_barrier();          // all waves done reading buf
        __builtin_amdgcn_sched_barrier(0);
        buf ^= 1;
    }
#undef STAGE

    // ---- epilogue: scalar stores (form proven time-neutral R3 vs R4)
#pragma unroll
    for (int mt = 0; mt < 6; ++mt)
#pragma unroll
        for (int nt = 0; nt < 6; ++nt) {
            int col = n0 + wc * 96 + nt * 16 + l15;
            float bb = bias[col];
#pragma unroll
            for (int r = 0; r < 4; ++r) {
                int row = m0 + wr * 96 + mt * 16 + g * 4 + r;
                if (row < M) {
                    if (OUTF32)
                        Cf[(size_t)row * ldc + col] = acc[mt][nt][r] + bb;
                    else
                        Cb[(size_t)row * ldc + col] = f2b(acc[mt][nt][r] + bb);
                }
            }
        }
}

// ---------------- attention: 1 wave per (window, head) -----------------------
__global__ __launch_bounds__(256) void k_attn(unsigned short* __restrict__ qkv,
        const float* __restrict__ mask, const float* __restrict__ btab, int win_base)
{
    extern __shared__ unsigned short sm[];
    const int tid = threadIdx.x;
    const int lane = tid & 63, wv = tid >> 6;
    const int l15 = lane & 15, g = lane >> 4;
    const int pair = blockIdx.x * 4 + wv;
    const int winloc = pair / 12;
    const int h = pair - winloc * 12;
    const int wimg = (win_base + winloc) & 63;
    const int co = h * 32;
    unsigned short* Vt = sm + wv * 6912;     // [32][72]  V^T
    unsigned short* Pw = Vt + 32 * 72;       // [64][72]  P
    unsigned short* src = qkv + (size_t)winloc * SEQ_N * QKV_N;

    for (int t = lane; t < 32 * 16; t += 64) {
        int c = t >> 4, kk = 48 + (t & 15);
        Vt[c * 72 + kk] = 0;
    }
    for (int t = lane; t < 49 * 4; t += 64) {
        int row = t >> 2, cb = (t & 3) * 8;
        const unsigned short* vp = src + (size_t)row * QKV_N + 768 + co + cb;
        ushort4 a = ((const ushort4*)vp)[0];
        ushort4 b = ((const ushort4*)vp)[1];
        Vt[(cb + 0) * 72 + row] = a.x; Vt[(cb + 1) * 72 + row] = a.y;
        Vt[(cb + 2) * 72 + row] = a.z; Vt[(cb + 3) * 72 + row] = a.w;
        Vt[(cb + 4) * 72 + row] = b.x; Vt[(cb + 5) * 72 + row] = b.y;
        Vt[(cb + 6) * 72 + row] = b.z; Vt[(cb + 7) * 72 + row] = b.w;
    }

    bf16x8 qf[4], kf[4];
#pragma unroll
    for (int mt = 0; mt < 4; ++mt) {
        int r = mt * 16 + l15; if (r > 48) r = 48;
        qf[mt] = ld8(src + (size_t)r * QKV_N + co + g * 8);
    }
#pragma unroll
    for (int nt = 0; nt < 4; ++nt) {
        int r = nt * 16 + l15; if (r > 48) r = 48;
        kf[nt] = ld8(src + (size_t)r * QKV_N + CH + co + g * 8);
    }

    f32x4 sa[4][4];
#pragma unroll
    for (int mt = 0; mt < 4; ++mt)
#pragma unroll
        for (int nt = 0; nt < 4; ++nt) sa[mt][nt] = (f32x4){0.f, 0.f, 0.f, 0.f};
#pragma unroll
    for (int mt = 0; mt < 4; ++mt)
#pragma unroll
        for (int nt = 0; nt < 4; ++nt)
            sa[mt][nt] = __builtin_amdgcn_mfma_f32_16x16x32_bf16(
                    qf[mt], kf[nt], sa[mt][nt], 0, 0, 0);

    int jj[4], jh[4], jw4[4];
#pragma unroll
    for (int nt = 0; nt < 4; ++nt) {
        int j = nt * 16 + l15;
        jj[nt] = j; jh[nt] = j / 7; jw4[nt] = j - (j / 7) * 7;
    }
    const float scale = 0.17677669529663687f;
#pragma unroll
    for (int mt = 0; mt < 4; ++mt) {
#pragma unroll
        for (int r = 0; r < 4; ++r) {
            int i = mt * 16 + g * 4 + r;
            int ic = i < 49 ? i : 48;
            int ih = ic / 7, iw = ic - (ic / 7) * 7;
            const float* mrow = mask + (size_t)wimg * 2401 + ic * 49;
            float sv[4];
#pragma unroll
            for (int nt = 0; nt < 4; ++nt) {
                float s = sa[mt][nt][r];
                if (jj[nt] < 49) {
                    int idx = (ih - jh[nt] + 6) * 13 + (iw - jw4[nt] + 6);
                    s = s * scale + btab[idx * 12 + h] + mrow[jj[nt]];
                } else s = -1e30f;
                sv[nt] = s;
            }
            float mx = fmaxf(fmaxf(sv[0], sv[1]), fmaxf(sv[2], sv[3]));
#pragma unroll
            for (int d = 1; d < 16; d <<= 1) mx = fmaxf(mx, __shfl_xor(mx, d));
            float sum = 0.f;
#pragma unroll
            for (int nt = 0; nt < 4; ++nt) { sv[nt] = __expf(sv[nt] - mx); sum += sv[nt]; }
#pragma unroll
            for (int d = 1; d < 16; d <<= 1) sum += __shfl_xor(sum, d);
            float inv = 1.0f / sum;
#pragma unroll
            for (int nt = 0; nt < 4; ++nt)
                Pw[i * 72 + nt * 16 + l15] = f2b(sv[nt] * inv);
        }
    }
    __syncthreads();

    f32x4 oa[4][2];
#pragma unroll
    for (int mt = 0; mt < 4; ++mt)
#pragma unroll
        for (int nt = 0; nt < 2; ++nt) oa[mt][nt] = (f32x4){0.f, 0.f, 0.f, 0.f};
#pragma unroll
    for (int ks = 0; ks < 2; ++ks) {
        bf16x8 pf[4];
#pragma unroll
        for (int mt = 0; mt < 4; ++mt)
            pf[mt] = ld8(Pw + (mt * 16 + l15) * 72 + ks * 32 + g * 8);
#pragma unroll
        for (int nt = 0; nt < 2; ++nt) {
            bf16x8 vf = ld8(Vt + (nt * 16 + l15) * 72 + ks * 32 + g * 8);
#pragma unroll
            for (int mt = 0; mt < 4; ++mt)
                oa[mt][nt] = __builtin_amdgcn_mfma_f32_16x16x32_bf16(
                        pf[mt], vf, oa[mt][nt], 0, 0, 0);
        }
    }

#pragma unroll
    for (int mt = 0; mt < 4; ++mt)
#pragma unroll
        for (int r = 0; r < 4; ++r) {
            int i = mt * 16 + g * 4 + r;
            if (i < 49) {
#pragma unroll
                for (int nt = 0; nt < 2; ++nt)
                    src[(size_t)i * QKV_N + co + nt * 16 + l15] = f2b(oa[mt][nt][r]);
            }
        }
}

extern "C" void kernel_launch(void* const* d_in, const int* in_sizes, int n_in,
                              void* d_out, int out_size, void* d_ws, size_t ws_size,
                              hipStream_t stream) {
    const float* x      = (const float*)d_in[0];
    const float* mask   = (const float*)d_in[1];
    const float* qkv_w  = (const float*)d_in[2];
    const float* qkv_b  = (const float*)d_in[3];
    const float* proj_w = (const float*)d_in[4];
    const float* proj_b = (const float*)d_in[5];
    const float* btab   = (const float*)d_in[6];
    float* out = (float*)d_out;

    unsigned short* wq_bt = (unsigned short*)d_ws;
    unsigned short* wp_bt = wq_bt + QKV_N * CH;
    unsigned short* base  = wp_bt + CH * CH;
    const size_t fixed = (size_t)(QKV_N * CH + CH * CH) * 2;
    const size_t unit  = (size_t)UNIT_ROWS * (CH + QKV_N) * 2;
    if (ws_size < fixed + unit) return;
    int upc = (int)((ws_size - fixed) / unit);
    if (upc > 64) upc = 64;
    unsigned short* xb  = base;
    unsigned short* qkv = base + (size_t)upc * UNIT_ROWS * CH;

    const int smem2 = 4 * 6912 * 2;   // 55,296 B -> 2 blocks/CU
    hipFuncSetAttribute(reinterpret_cast<const void*>(k_attn),
                        hipFuncAttributeMaxDynamicSharedMemorySize, smem2);

    dim3 blk(256);
    k_cvt_w<<<dim3((QKV_N * CH + 255) / 256), blk, 0, stream>>>(qkv_w, proj_w, wq_bt, wp_bt);

    for (int u0 = 0; u0 < 64; u0 += upc) {
        int units = (64 - u0) < upc ? (64 - u0) : upc;
        int m_base = u0 * UNIT_ROWS;
        int Mc = units * UNIT_ROWS;
        int mtiles = (Mc + 191) / 192;
        k_cvt<<<dim3(2048), blk, 0, stream>>>(x + (size_t)m_base * CH, xb, Mc * 48);
        k_gemm<0><<<dim3(mtiles * 3), dim3(512), 0, stream>>>(
                xb, CH, wq_bt, CH, qkv_b, qkv, nullptr, QKV_N, Mc, 3, mtiles);
        k_attn<<<dim3(units * 192), blk, smem2, stream>>>(qkv, mask, btab, u0);
        k_gemm<1><<<dim3(mtiles * 1), dim3(512), 0, stream>>>(
                qkv, QKV_N, wp_bt, CH, proj_b, nullptr, out + (size_t)m_base * CH,
                CH, Mc, 1, mtiles);
    }
}

// Round 10
// 1081.334 us; speedup vs baseline: 1.4255x; 1.0506x over previous
//
#include <hip/hip_runtime.h>
#include <hip/hip_bf16.h>

// WindowAttention (Swin) on MI355X — round 10
//   k_gemm rewritten on the m201 8-phase-family schedule: BM=256 BN=128 BK=64,
//   8 waves (4Mx2N, 64x64/wave), 3-buffer LDS (144KB) depth-2 prefetch,
//   counted vmcnt(6) + single s_barrier per K-tile, T2 XOR swizzle
//   (source-side for global_load_lds + same XOR on ds_read), T5 setprio.
//   NOTE (post-mortem): all prior top-5 rows were k_qkv replays; proj was
//   never in top-5. qkv at MfmaUtil 18% = 5x off MFMA roofline (floor ~85us).
//   k_attn / k_cvt / k_cvt_w unchanged.

typedef __attribute__((ext_vector_type(8))) short bf16x8;
typedef __attribute__((ext_vector_type(4))) float f32x4;

#define SEQ_N  49
#define CH     384
#define QKV_N  1152
#define UNIT_ROWS 3136   // 64 windows * 49 rows

__device__ __forceinline__ unsigned short f2b(float f) {
    union { float f; unsigned int u; } v; v.f = f;
    return (unsigned short)((v.u + 0x7FFFu + ((v.u >> 16) & 1u)) >> 16);
}

__device__ __forceinline__ bf16x8 ld8(const unsigned short* p) {
    return *(const bf16x8*)p;
}

// async global->LDS, 16B/lane; lane i lands at lds_base + i*16 (HW-fixed)
__device__ __forceinline__ void gload16(const unsigned short* g, unsigned short* l) {
    __builtin_amdgcn_global_load_lds(
        (const __attribute__((address_space(1))) unsigned int*)g,
        (__attribute__((address_space(3))) unsigned int*)l, 16, 0, 0);
}

// bijective XCD-chunking swizzle (m204)
__device__ __forceinline__ int xcd_swizzle(int orig, int T) {
    int q = T >> 3, r = T & 7;
    int xcd = orig & 7, idx = orig >> 3;
    return (xcd < r ? xcd * (q + 1) : r * (q + 1) + (xcd - r) * q) + idx;
}

// ---------------- weight convert+transpose: Bt[n][k] = bf16(W[k][n]) --------
__global__ __launch_bounds__(256) void k_cvt_w(const float* __restrict__ wq,
        const float* __restrict__ wp, unsigned short* __restrict__ oq,
        unsigned short* __restrict__ op)
{
    int t = blockIdx.x * 256 + threadIdx.x;
    if (t < QKV_N * CH) {
        int n = t / CH, k = t - n * CH;
        oq[t] = f2b(wq[(size_t)k * QKV_N + n]);
    }
    if (t < CH * CH) {
        int n = t / CH, k = t - n * CH;
        op[t] = f2b(wp[(size_t)k * CH + n]);
    }
}

// ---------------- x fp32 -> bf16 (vectorized, grid-stride) -------------------
__global__ __launch_bounds__(256) void k_cvt(const float* __restrict__ in,
        unsigned short* __restrict__ outp, int n8)
{
    int stride = gridDim.x * 256;
    for (int i = blockIdx.x * 256 + threadIdx.x; i < n8; i += stride) {
        const float4* p = (const float4*)(in + (size_t)i * 8);
        float4 a = p[0], b = p[1];
        uint4 v;
        v.x = (unsigned)f2b(a.x) | ((unsigned)f2b(a.y) << 16);
        v.y = (unsigned)f2b(a.z) | ((unsigned)f2b(a.w) << 16);
        v.z = (unsigned)f2b(b.x) | ((unsigned)f2b(b.y) << 16);
        v.w = (unsigned)f2b(b.z) | ((unsigned)f2b(b.w) << 16);
        *(uint4*)(outp + (size_t)i * 8) = v;
    }
}

// ---------------- pipelined GEMM: C[M][ldc] = A @ Bt^T + bias ----------------
// A bf16 row-major [M][lda] (cols 0..K-1 used), Bt bf16 n-major [N][K].
// BM=256 BN=128 BK=64; 3-buf LDS; per-buf: A 256x64 (16384 el) + B 128x64
// (8192 el) = 49152 B.  LDS rows are 128B; chunk (16B unit) XOR-swizzled by
// (row&7) on BOTH the gload source address and the ds_read address.
template<int OUTF32>
__global__ __launch_bounds__(512, 1) void k_gemm(
        const unsigned short* __restrict__ A, int lda,
        const unsigned short* __restrict__ Bt, int K,
        const float* __restrict__ bias,
        unsigned short* __restrict__ Cb, float* __restrict__ Cf, int ldc,
        int M, int ntiles, int mtiles)
{
    extern __shared__ unsigned short smem[];   // 3 * 24576 elems
    const int wg = xcd_swizzle(blockIdx.x, mtiles * ntiles);
    const int m0 = (wg / ntiles) * 256;
    const int n0 = (wg % ntiles) * 128;
    const int tid = threadIdx.x;
    const int lane = tid & 63, wv = tid >> 6;
    const int wr = wv >> 1, wn = wv & 1;       // wave = 64x64 at (wr*64, wn*64)
    const int l15 = lane & 15, g = lane >> 4;

    f32x4 acc[4][4];
#pragma unroll
    for (int a = 0; a < 4; ++a)
#pragma unroll
        for (int b = 0; b < 4; ++b) acc[a][b] = (f32x4){0.f, 0.f, 0.f, 0.f};

    // ---- staging descriptors: each gload covers 8 rows x 8 chunks (1 KB)
    const int lrow8 = lane >> 3, lchunk = lane & 7;
    const unsigned short* aSrc[4]; int aLds[4];
#pragma unroll
    for (int i2 = 0; i2 < 4; ++i2) {
        int row = wv * 32 + i2 * 8 + lrow8;          // 0..255
        int grow = m0 + row; if (grow > M - 1) grow = M - 1;
        aSrc[i2] = A + (size_t)grow * lda + ((lchunk ^ (row & 7)) * 8);
        aLds[i2] = (wv * 32 + i2 * 8) * 64;          // wave-uniform
    }
    const unsigned short* bSrc[2]; int bLds[2];
#pragma unroll
    for (int i2 = 0; i2 < 2; ++i2) {
        int row = wv * 16 + i2 * 8 + lrow8;          // 0..127
        bSrc[i2] = Bt + (size_t)(n0 + row) * K + ((lchunk ^ (row & 7)) * 8);
        bLds[i2] = 16384 + (wv * 16 + i2 * 8) * 64;  // wave-uniform
    }

#define STAGE(kc, b) do { unsigned short* pb = smem + (b) * 24576;   \
        gload16(aSrc[0] + (kc), pb + aLds[0]);                        \
        gload16(aSrc[1] + (kc), pb + aLds[1]);                        \
        gload16(aSrc[2] + (kc), pb + aLds[2]);                        \
        gload16(aSrc[3] + (kc), pb + aLds[3]);                        \
        gload16(bSrc[0] + (kc), pb + bLds[0]);                        \
        gload16(bSrc[1] + (kc), pb + bLds[1]); } while (0)

    const int ns = K >> 6;                 // 6 (K=384)
    STAGE(0, 0);
    STAGE(64, 1);

    for (int t = 0; t < ns; ++t) {
        if (t + 1 < ns) asm volatile("s_waitcnt vmcnt(6)" ::: "memory");
        else            asm volatile("s_waitcnt vmcnt(0)" ::: "memory");
        __builtin_amdgcn_s_barrier();          // tile t staged for all waves
        __builtin_amdgcn_sched_barrier(0);     // no LDS-read hoist above barrier
        if (t + 2 < ns) STAGE((t + 2) * 64, (t + 2) % 3);
        const unsigned short* pb = smem + (t % 3) * 24576;
#pragma unroll
        for (int kh = 0; kh < 2; ++kh) {
            bf16x8 af[4], bfr[4];
#pragma unroll
            for (int mt = 0; mt < 4; ++mt) {
                int row = wr * 64 + mt * 16 + l15;
                af[mt] = ld8(pb + row * 64 + (((kh * 4 + g) ^ (row & 7)) * 8));
            }
#pragma unroll
            for (int nt = 0; nt < 4; ++nt) {
                int row = wn * 64 + nt * 16 + l15;
                bfr[nt] = ld8(pb + 16384 + row * 64 + (((kh * 4 + g) ^ (row & 7)) * 8));
            }
            __builtin_amdgcn_s_setprio(1);
#pragma unroll
            for (int mt = 0; mt < 4; ++mt)
#pragma unroll
                for (int nt = 0; nt < 4; ++nt)
                    acc[mt][nt] = __builtin_amdgcn_mfma_f32_16x16x32_bf16(
                            af[mt], bfr[nt], acc[mt][nt], 0, 0, 0);
            __builtin_amdgcn_s_setprio(0);
        }
    }
#undef STAGE

    // ---- epilogue: scalar stores (form proven time-neutral R3 vs R4)
#pragma unroll
    for (int mt = 0; mt < 4; ++mt)
#pragma unroll
        for (int nt = 0; nt < 4; ++nt) {
            int col = n0 + wn * 64 + nt * 16 + l15;
            float bb = bias[col];
#pragma unroll
            for (int r = 0; r < 4; ++r) {
                int row = m0 + wr * 64 + mt * 16 + g * 4 + r;
                if (row < M) {
                    if (OUTF32)
                        Cf[(size_t)row * ldc + col] = acc[mt][nt][r] + bb;
                    else
                        Cb[(size_t)row * ldc + col] = f2b(acc[mt][nt][r] + bb);
                }
            }
        }
}

// ---------------- attention: 1 wave per (window, head) -----------------------
__global__ __launch_bounds__(256) void k_attn(unsigned short* __restrict__ qkv,
        const float* __restrict__ mask, const float* __restrict__ btab, int win_base)
{
    extern __shared__ unsigned short sm[];
    const int tid = threadIdx.x;
    const int lane = tid & 63, wv = tid >> 6;
    const int l15 = lane & 15, g = lane >> 4;
    const int pair = blockIdx.x * 4 + wv;
    const int winloc = pair / 12;
    const int h = pair - winloc * 12;
    const int wimg = (win_base + winloc) & 63;
    const int co = h * 32;
    unsigned short* Vt = sm + wv * 6912;     // [32][72]  V^T
    unsigned short* Pw = Vt + 32 * 72;       // [64][72]  P
    unsigned short* src = qkv + (size_t)winloc * SEQ_N * QKV_N;

    for (int t = lane; t < 32 * 16; t += 64) {
        int c = t >> 4, kk = 48 + (t & 15);
        Vt[c * 72 + kk] = 0;
    }
    for (int t = lane; t < 49 * 4; t += 64) {
        int row = t >> 2, cb = (t & 3) * 8;
        const unsigned short* vp = src + (size_t)row * QKV_N + 768 + co + cb;
        ushort4 a = ((const ushort4*)vp)[0];
        ushort4 b = ((const ushort4*)vp)[1];
        Vt[(cb + 0) * 72 + row] = a.x; Vt[(cb + 1) * 72 + row] = a.y;
        Vt[(cb + 2) * 72 + row] = a.z; Vt[(cb + 3) * 72 + row] = a.w;
        Vt[(cb + 4) * 72 + row] = b.x; Vt[(cb + 5) * 72 + row] = b.y;
        Vt[(cb + 6) * 72 + row] = b.z; Vt[(cb + 7) * 72 + row] = b.w;
    }

    bf16x8 qf[4], kf[4];
#pragma unroll
    for (int mt = 0; mt < 4; ++mt) {
        int r = mt * 16 + l15; if (r > 48) r = 48;
        qf[mt] = ld8(src + (size_t)r * QKV_N + co + g * 8);
    }
#pragma unroll
    for (int nt = 0; nt < 4; ++nt) {
        int r = nt * 16 + l15; if (r > 48) r = 48;
        kf[nt] = ld8(src + (size_t)r * QKV_N + CH + co + g * 8);
    }

    f32x4 sa[4][4];
#pragma unroll
    for (int mt = 0; mt < 4; ++mt)
#pragma unroll
        for (int nt = 0; nt < 4; ++nt) sa[mt][nt] = (f32x4){0.f, 0.f, 0.f, 0.f};
#pragma unroll
    for (int mt = 0; mt < 4; ++mt)
#pragma unroll
        for (int nt = 0; nt < 4; ++nt)
            sa[mt][nt] = __builtin_amdgcn_mfma_f32_16x16x32_bf16(
                    qf[mt], kf[nt], sa[mt][nt], 0, 0, 0);

    int jj[4], jh[4], jw4[4];
#pragma unroll
    for (int nt = 0; nt < 4; ++nt) {
        int j = nt * 16 + l15;
        jj[nt] = j; jh[nt] = j / 7; jw4[nt] = j - (j / 7) * 7;
    }
    const float scale = 0.17677669529663687f;
#pragma unroll
    for (int mt = 0; mt < 4; ++mt) {
#pragma unroll
        for (int r = 0; r < 4; ++r) {
            int i = mt * 16 + g * 4 + r;
            int ic = i < 49 ? i : 48;
            int ih = ic / 7, iw = ic - (ic / 7) * 7;
            const float* mrow = mask + (size_t)wimg * 2401 + ic * 49;
            float sv[4];
#pragma unroll
            for (int nt = 0; nt < 4; ++nt) {
                float s = sa[mt][nt][r];
                if (jj[nt] < 49) {
                    int idx = (ih - jh[nt] + 6) * 13 + (iw - jw4[nt] + 6);
                    s = s * scale + btab[idx * 12 + h] + mrow[jj[nt]];
                } else s = -1e30f;
                sv[nt] = s;
            }
            float mx = fmaxf(fmaxf(sv[0], sv[1]), fmaxf(sv[2], sv[3]));
#pragma unroll
            for (int d = 1; d < 16; d <<= 1) mx = fmaxf(mx, __shfl_xor(mx, d));
            float sum = 0.f;
#pragma unroll
            for (int nt = 0; nt < 4; ++nt) { sv[nt] = __expf(sv[nt] - mx); sum += sv[nt]; }
#pragma unroll
            for (int d = 1; d < 16; d <<= 1) sum += __shfl_xor(sum, d);
            float inv = 1.0f / sum;
#pragma unroll
            for (int nt = 0; nt < 4; ++nt)
                Pw[i * 72 + nt * 16 + l15] = f2b(sv[nt] * inv);
        }
    }
    __syncthreads();

    f32x4 oa[4][2];
#pragma unroll
    for (int mt = 0; mt < 4; ++mt)
#pragma unroll
        for (int nt = 0; nt < 2; ++nt) oa[mt][nt] = (f32x4){0.f, 0.f, 0.f, 0.f};
#pragma unroll
    for (int ks = 0; ks < 2; ++ks) {
        bf16x8 pf[4];
#pragma unroll
        for (int mt = 0; mt < 4; ++mt)
            pf[mt] = ld8(Pw + (mt * 16 + l15) * 72 + ks * 32 + g * 8);
#pragma unroll
        for (int nt = 0; nt < 2; ++nt) {
            bf16x8 vf = ld8(Vt + (nt * 16 + l15) * 72 + ks * 32 + g * 8);
#pragma unroll
            for (int mt = 0; mt < 4; ++mt)
                oa[mt][nt] = __builtin_amdgcn_mfma_f32_16x16x32_bf16(
                        pf[mt], vf, oa[mt][nt], 0, 0, 0);
        }
    }

#pragma unroll
    for (int mt = 0; mt < 4; ++mt)
#pragma unroll
        for (int r = 0; r < 4; ++r) {
            int i = mt * 16 + g * 4 + r;
            if (i < 49) {
#pragma unroll
                for (int nt = 0; nt < 2; ++nt)
                    src[(size_t)i * QKV_N + co + nt * 16 + l15] = f2b(oa[mt][nt][r]);
            }
        }
}

extern "C" void kernel_launch(void* const* d_in, const int* in_sizes, int n_in,
                              void* d_out, int out_size, void* d_ws, size_t ws_size,
                              hipStream_t stream) {
    const float* x      = (const float*)d_in[0];
    const float* mask   = (const float*)d_in[1];
    const float* qkv_w  = (const float*)d_in[2];
    const float* qkv_b  = (const float*)d_in[3];
    const float* proj_w = (const float*)d_in[4];
    const float* proj_b = (const float*)d_in[5];
    const float* btab   = (const float*)d_in[6];
    float* out = (float*)d_out;

    unsigned short* wq_bt = (unsigned short*)d_ws;
    unsigned short* wp_bt = wq_bt + QKV_N * CH;
    unsigned short* base  = wp_bt + CH * CH;
    const size_t fixed = (size_t)(QKV_N * CH + CH * CH) * 2;
    const size_t unit  = (size_t)UNIT_ROWS * (CH + QKV_N) * 2;
    if (ws_size < fixed + unit) return;
    int upc = (int)((ws_size - fixed) / unit);
    if (upc > 64) upc = 64;
    unsigned short* xb  = base;
    unsigned short* qkv = base + (size_t)upc * UNIT_ROWS * CH;

    const int smem2 = 4 * 6912 * 2;   // 55,296 B -> 2 blocks/CU (attn)
    hipFuncSetAttribute(reinterpret_cast<const void*>(k_attn),
                        hipFuncAttributeMaxDynamicSharedMemorySize, smem2);
    const int smemG = 3 * 24576 * 2;  // 147,456 B (gemm)
    hipFuncSetAttribute(reinterpret_cast<const void*>(k_gemm<0>),
                        hipFuncAttributeMaxDynamicSharedMemorySize, smemG);
    hipFuncSetAttribute(reinterpret_cast<const void*>(k_gemm<1>),
                        hipFuncAttributeMaxDynamicSharedMemorySize, smemG);

    dim3 blk(256);
    k_cvt_w<<<dim3((QKV_N * CH + 255) / 256), blk, 0, stream>>>(qkv_w, proj_w, wq_bt, wp_bt);

    for (int u0 = 0; u0 < 64; u0 += upc) {
        int units = (64 - u0) < upc ? (64 - u0) : upc;
        int m_base = u0 * UNIT_ROWS;
        int Mc = units * UNIT_ROWS;
        int mtiles = (Mc + 255) / 256;
        k_cvt<<<dim3(2048), blk, 0, stream>>>(x + (size_t)m_base * CH, xb, Mc * 48);
        k_gemm<0><<<dim3(mtiles * 9), dim3(512), smemG, stream>>>(
                xb, CH, wq_bt, CH, qkv_b, qkv, nullptr, QKV_N, Mc, 9, mtiles);
        k_attn<<<dim3(units * 192), blk, smem2, stream>>>(qkv, mask, btab, u0);
        k_gemm<1><<<dim3(mtiles * 3), dim3(512), smemG, stream>>>(
                qkv, QKV_N, wp_bt, CH, proj_b, nullptr, out + (size_t)m_base * CH,
                CH, Mc, 3, mtiles);
    }
}